// Round 6
// baseline (160.341 us; speedup 1.0000x reference)
//
#include <hip/hip_runtime.h>
#include <math.h>

#define NPOS  16384
#define LBAG  30
#define NFEAT 40960
#define HDIM  512          // per side
#define MT    16           // positions per block

typedef short bf16x8 __attribute__((ext_vector_type(8)));
typedef float f32x4  __attribute__((ext_vector_type(4)));

__device__ __forceinline__ unsigned int f2bf(float f) {
    unsigned int u = __float_as_uint(f);
    return (u + 0x7fffu + ((u >> 16) & 1u)) >> 16;
}
__device__ __forceinline__ float clip01(float v) { return fminf(fmaxf(v, 0.f), 1.f); }

// ---------------------------------------------------------------------------
// Prep 1: emb fp32 -> bf16 (pairs packed in uint). 84MB read + 42MB write.
// ---------------------------------------------------------------------------
__global__ __launch_bounds__(256) void cvt_emb(const float* __restrict__ src,
                                               unsigned int* __restrict__ dst) {
    const int nchunk = NFEAT * HDIM / 8;
    int c = blockIdx.x * 256 + threadIdx.x;
    const int stride = gridDim.x * 256;
    for (; c < nchunk; c += stride) {
        float4 f0 = ((const float4*)src)[(size_t)c * 2];
        float4 f1 = ((const float4*)src)[(size_t)c * 2 + 1];
        uint4 o;
        o.x = f2bf(f0.x) | (f2bf(f0.y) << 16);
        o.y = f2bf(f0.z) | (f2bf(f0.w) << 16);
        o.z = f2bf(f1.x) | (f2bf(f1.y) << 16);
        o.w = f2bf(f1.z) | (f2bf(f1.w) << 16);
        ((uint4*)dst)[c] = o;
    }
}

// ---------------------------------------------------------------------------
// Prep 2: W1 [128][1024] fp32 -> bf16 in MFMA B-fragment order.
//   B[k][j] = W1[j][k], j = nf*16 + (lane&15), k = ks*32 + (lane>>4)*8 + b
// ---------------------------------------------------------------------------
__global__ __launch_bounds__(256) void prep_w1(const float* __restrict__ W1,
                                               unsigned int* __restrict__ dst) {
    int c = blockIdx.x * 256 + threadIdx.x;
    if (c >= 8 * 32 * 64) return;
    int l  = c & 63;
    int ks = (c >> 6) & 31;
    int nf = c >> 11;
    int o  = nf * 16 + (l & 15);
    int kb = ks * 32 + (l >> 4) * 8;
    float4 f0 = *(const float4*)(W1 + (size_t)o * 1024 + kb);
    float4 f1 = *(const float4*)(W1 + (size_t)o * 1024 + kb + 4);
    uint4 v;
    v.x = f2bf(f0.x) | (f2bf(f0.y) << 16);
    v.y = f2bf(f0.z) | (f2bf(f0.w) << 16);
    v.z = f2bf(f1.x) | (f2bf(f1.y) << 16);
    v.w = f2bf(f1.z) | (f2bf(f1.w) << 16);
    ((uint4*)dst)[c] = v;
}

// ---------------------------------------------------------------------------
// Fused kernel, round 6: MT=16 for occupancy. r5 evidence: 20% occupancy
// (73KB LDS -> 2 blocks/CU), 3.15 TB/s effective gather BW, VALU 26%,
// MFMA 1% -> latency-bound random gather. MT=16 halves LDS to 36.6KB ->
// 4 blocks/CU -> 16 waves/CU (the VGPR=128 cap), doubling loads in flight.
//
// LDS map (36608 B):
//   [0,32768)      phase 1: x tile, 16 rows x 2048 B, XOR-swizzled
//                  phase 2: h1[16][132] | w2[32][132] | h2[16][33]  (27456 B)
//   [32768,36608)  sidx[32 bags][30] int
//
// Swizzle: byte = row*2048 + (col ^ ((row&7)<<4))  (write + A-frag read)
// MFMA 16x16x32_bf16: A row=lane&15, k=(lane>>4)*8+b; C/D col=lane&15,
// row=(lane>>4)*4+reg [m89]. Wave w covers nf = 2w, 2w+1; single M-frag.
// ---------------------------------------------------------------------------
__global__ __launch_bounds__(256, 4) void nnue_fused(
    const int* __restrict__ stm_idx, const int* __restrict__ nstm_idx,
    const unsigned int* __restrict__ embbf,     // [NFEAT][512] bf16
    const unsigned int* __restrict__ w1f,       // frag-ordered bf16
    const float* __restrict__ b1,
    const float* __restrict__ W2, const float* __restrict__ b2,
    const float* __restrict__ W3, const float* __restrict__ b3,
    float* __restrict__ out)
{
    __shared__ __align__(16) char smem[36608];
    char* xb   = smem;
    int*  sidx = (int*)(smem + 32768);
    float* h1  = (float*)smem;                  // [16][132]
    float* w2  = (float*)smem + 16 * 132;       // [32][132]
    float* h2  = (float*)smem + 48 * 132;       // [16][33]

    const int t    = threadIdx.x;               // 0..255
    const int pblk = blockIdx.x * MT;
    const int w    = t >> 6;                    // wave 0..3
    const int lane = t & 63;

    // ---- stage bag indices: sidx[bag*30 + l], bag = p*2+side ----
#pragma unroll
    for (int i = 0; i < 4; ++i) {
        int e = t + i * 256;                    // 0..1023
        if (e < 480) {
            int p = e / 30, l = e - p * 30;
            sidx[p * 60 + l] = stm_idx[(pblk + p) * 30 + l];
        } else if (e < 960) {
            int e2 = e - 480;
            int p = e2 / 30, l = e2 - p * 30;
            sidx[p * 60 + 30 + l] = nstm_idx[(pblk + p) * 30 + l];
        }
    }
    __syncthreads();

    // ---- bag gather + sum + clip -> swizzled bf16 x tile ----
    // wave w: bags 8w..8w+7; lane covers 8 bf16 cols of the 1024-col row
#pragma unroll 1
    for (int i = 0; i < 8; ++i) {
        const int bag  = w * 8 + i;
        const int p    = bag >> 1;
        const int side = bag & 1;
        const int* ids = sidx + bag * 30;
        float ac[8];
#pragma unroll
        for (int j = 0; j < 8; ++j) ac[j] = 0.f;
#pragma unroll
        for (int l = 0; l < 30; ++l) {
            const uint4 v = *(const uint4*)(embbf + (size_t)ids[l] * 256 + (lane << 2));
            ac[0] += __uint_as_float(v.x << 16);
            ac[1] += __uint_as_float(v.x & 0xffff0000u);
            ac[2] += __uint_as_float(v.y << 16);
            ac[3] += __uint_as_float(v.y & 0xffff0000u);
            ac[4] += __uint_as_float(v.z << 16);
            ac[5] += __uint_as_float(v.z & 0xffff0000u);
            ac[6] += __uint_as_float(v.w << 16);
            ac[7] += __uint_as_float(v.w & 0xffff0000u);
        }
#pragma unroll
        for (int j = 0; j < 8; ++j) ac[j] = clip01(ac[j]);
        uint4 pk;
        pk.x = f2bf(ac[0]) | (f2bf(ac[1]) << 16);
        pk.y = f2bf(ac[2]) | (f2bf(ac[3]) << 16);
        pk.z = f2bf(ac[4]) | (f2bf(ac[5]) << 16);
        pk.w = f2bf(ac[6]) | (f2bf(ac[7]) << 16);
        const int col  = side * 1024 + lane * 16;
        const int addr = p * 2048 + (col ^ ((p & 7) << 4));
        *(uint4*)(xb + addr) = pk;
    }
    __syncthreads();

    // ---- layer1 GEMM via MFMA (M=16, N=128, K=1024) ----
    const int l15 = lane & 15, lg = lane >> 4, lq = lane & 7;
    f32x4 acc0 = {}, acc1 = {};
    const int arow = l15 * 2048;
    const bf16x8* w1v = (const bf16x8*)w1f;
#pragma unroll 4
    for (int ks = 0; ks < 32; ++ks) {
        const int acol = (ks * 64 + lg * 16) ^ (lq << 4);
        bf16x8 a0  = *(const bf16x8*)(xb + arow + acol);
        bf16x8 bf0 = w1v[((2 * w + 0) * 32 + ks) * 64 + lane];
        bf16x8 bf1 = w1v[((2 * w + 1) * 32 + ks) * 64 + lane];
        acc0 = __builtin_amdgcn_mfma_f32_16x16x32_bf16(a0, bf0, acc0, 0, 0, 0);
        acc1 = __builtin_amdgcn_mfma_f32_16x16x32_bf16(a0, bf1, acc1, 0, 0, 0);
    }
    __syncthreads();   // x tile dead; smem becomes h1/w2/h2

    // ---- epilogue: bias + clip -> h1[16][132] ----
    {
        const int o0 = (2 * w + 0) * 16 + l15;
        const int o1 = (2 * w + 1) * 16 + l15;
        const float bb0 = b1[o0], bb1 = b1[o1];
#pragma unroll
        for (int r = 0; r < 4; ++r) {
            int p0 = lg * 4 + r;                // 0..15
            h1[p0 * 132 + o0] = clip01(acc0[r] + bb0);
            h1[p0 * 132 + o1] = clip01(acc1[r] + bb1);
        }
    }
    // stage W2 (32x128): 4096 floats, 16 per thread
#pragma unroll
    for (int i = 0; i < 16; ++i) {
        int f = t + i * 256;
        int o = f >> 7, k = f & 127;
        w2[o * 132 + k] = W2[o * 128 + k];
    }
    __syncthreads();

    // ---- layer2: 16 pos x 32 out; thread -> pos t>>4, 2 outputs ----
    {
        const int p2 = t >> 4;
        const int ob = (t & 15) * 2;
        float s0 = b2[ob], s1 = b2[ob + 1];
#pragma unroll
        for (int k4 = 0; k4 < 32; ++k4) {
            float4 h4 = *(const float4*)(h1 + p2 * 132 + k4 * 4);
            float4 wa = *(const float4*)(w2 + ob * 132 + k4 * 4);
            float4 wb = *(const float4*)(w2 + (ob + 1) * 132 + k4 * 4);
            s0 += h4.x * wa.x + h4.y * wa.y + h4.z * wa.z + h4.w * wa.w;
            s1 += h4.x * wb.x + h4.y * wb.y + h4.z * wb.z + h4.w * wb.w;
        }
        h2[p2 * 33 + ob]     = clip01(s0);
        h2[p2 * 33 + ob + 1] = clip01(s1);
    }
    __syncthreads();

    // ---- layer3 + tanh ----
    if (t < MT) {
        float s = b3[0];
#pragma unroll
        for (int k = 0; k < 32; ++k) s += h2[t * 33 + k] * W3[k];
        out[pblk + t] = tanhf(s);
    }
}

// ---------------------------------------------------------------------------
extern "C" void kernel_launch(void* const* d_in, const int* in_sizes, int n_in,
                              void* d_out, int out_size, void* d_ws, size_t ws_size,
                              hipStream_t stream) {
    const int*   stm_idx  = (const int*)  d_in[0];
    const int*   nstm_idx = (const int*)  d_in[2];
    const float* emb      = (const float*)d_in[4];
    const float* W1       = (const float*)d_in[5];
    const float* b1       = (const float*)d_in[6];
    const float* W2       = (const float*)d_in[7];
    const float* b2       = (const float*)d_in[8];
    const float* W3       = (const float*)d_in[9];
    const float* b3       = (const float*)d_in[10];
    float*       out      = (float*)d_out;

    unsigned int* embbf = (unsigned int*)d_ws;                       // 41,943,040 B
    unsigned int* w1f   = (unsigned int*)((char*)d_ws + 41943040);   // 262,144 B

    cvt_emb<<<2048, 256, 0, stream>>>(emb, embbf);
    prep_w1<<<64, 256, 0, stream>>>(W1, w1f);
    nnue_fused<<<NPOS / MT, 256, 0, stream>>>(stm_idx, nstm_idx, embbf, w1f,
                                              b1, W2, b2, W3, b3, out);
}

// Round 7
// 155.710 us; speedup vs baseline: 1.0297x; 1.0297x over previous
//
#include <hip/hip_runtime.h>
#include <math.h>

#define NPOS  16384
#define LBAG  30
#define NFEAT 40960
#define HDIM  512          // per side
#define MT    16           // positions per block

typedef short bf16x8 __attribute__((ext_vector_type(8)));
typedef float f32x4  __attribute__((ext_vector_type(4)));

__device__ __forceinline__ unsigned int f2bf(float f) {
    unsigned int u = __float_as_uint(f);
    return (u + 0x7fffu + ((u >> 16) & 1u)) >> 16;
}
__device__ __forceinline__ float clip01(float v) { return fminf(fmaxf(v, 0.f), 1.f); }

// ---------------------------------------------------------------------------
// Prep 1: emb fp32 -> bf16 (pairs packed in uint). 84MB read + 42MB write.
// ---------------------------------------------------------------------------
__global__ __launch_bounds__(256) void cvt_emb(const float* __restrict__ src,
                                               unsigned int* __restrict__ dst) {
    const int nchunk = NFEAT * HDIM / 8;
    int c = blockIdx.x * 256 + threadIdx.x;
    const int stride = gridDim.x * 256;
    for (; c < nchunk; c += stride) {
        float4 f0 = ((const float4*)src)[(size_t)c * 2];
        float4 f1 = ((const float4*)src)[(size_t)c * 2 + 1];
        uint4 o;
        o.x = f2bf(f0.x) | (f2bf(f0.y) << 16);
        o.y = f2bf(f0.z) | (f2bf(f0.w) << 16);
        o.z = f2bf(f1.x) | (f2bf(f1.y) << 16);
        o.w = f2bf(f1.z) | (f2bf(f1.w) << 16);
        ((uint4*)dst)[c] = o;
    }
}

// ---------------------------------------------------------------------------
// Prep 2: W1 [128][1024] fp32 -> bf16 in MFMA B-fragment order.
//   B[k][j] = W1[j][k], j = nf*16 + (lane&15), k = ks*32 + (lane>>4)*8 + b
// ---------------------------------------------------------------------------
__global__ __launch_bounds__(256) void prep_w1(const float* __restrict__ W1,
                                               unsigned int* __restrict__ dst) {
    int c = blockIdx.x * 256 + threadIdx.x;
    if (c >= 8 * 32 * 64) return;
    int l  = c & 63;
    int ks = (c >> 6) & 31;
    int nf = c >> 11;
    int o  = nf * 16 + (l & 15);
    int kb = ks * 32 + (l >> 4) * 8;
    float4 f0 = *(const float4*)(W1 + (size_t)o * 1024 + kb);
    float4 f1 = *(const float4*)(W1 + (size_t)o * 1024 + kb + 4);
    uint4 v;
    v.x = f2bf(f0.x) | (f2bf(f0.y) << 16);
    v.y = f2bf(f0.z) | (f2bf(f0.w) << 16);
    v.z = f2bf(f1.x) | (f2bf(f1.y) << 16);
    v.w = f2bf(f1.z) | (f2bf(f1.w) << 16);
    ((uint4*)dst)[c] = v;
}

// ---------------------------------------------------------------------------
// Fused kernel, round 7: explicit gather MLP. r5/r6 evidence: gather rate
// pinned at 11.6 B/cyc/CU regardless of occupancy (20%->44.5%); per-wave
// period ~1400 cyc/load matches serialized ds_read(idx)->global_load->unpack.
// This round: 4 concurrent bags x 2-row chunks per wave = 8 independent
// global_load_dwordx4 in flight; index ds_reads batched before the loads.
// ~100 VGPR (acc 32 + buf 32 + idx 8 + misc), under the 4-waves/SIMD cap.
//
// LDS map (36608 B): [0,32768) x tile (phase1) / h1|w2|h2 (phase2);
//                    [32768,36608) sidx[32 bags][30].
// Swizzle: byte = row*2048 + (col ^ ((row&7)<<4)) on write and A-frag read.
// MFMA 16x16x32_bf16: A row=lane&15, k=(lane>>4)*8+b; C/D col=lane&15,
// row=(lane>>4)*4+reg [m89]. Wave w covers nf = 2w, 2w+1.
// ---------------------------------------------------------------------------
__global__ __launch_bounds__(256, 4) void nnue_fused(
    const int* __restrict__ stm_idx, const int* __restrict__ nstm_idx,
    const unsigned int* __restrict__ embbf,     // [NFEAT][512] bf16
    const unsigned int* __restrict__ w1f,       // frag-ordered bf16
    const float* __restrict__ b1,
    const float* __restrict__ W2, const float* __restrict__ b2,
    const float* __restrict__ W3, const float* __restrict__ b3,
    float* __restrict__ out)
{
    __shared__ __align__(16) char smem[36608];
    char* xb   = smem;
    int*  sidx = (int*)(smem + 32768);
    float* h1  = (float*)smem;                  // [16][132]
    float* w2  = (float*)smem + 16 * 132;       // [32][132]
    float* h2  = (float*)smem + 48 * 132;       // [16][33]

    const int t    = threadIdx.x;               // 0..255
    const int pblk = blockIdx.x * MT;
    const int w    = t >> 6;                    // wave 0..3
    const int lane = t & 63;

    // ---- stage bag indices: sidx[bag*30 + l], bag = p*2+side ----
#pragma unroll
    for (int i = 0; i < 4; ++i) {
        int e = t + i * 256;                    // 0..1023
        if (e < 480) {
            int p = e / 30, l = e - p * 30;
            sidx[p * 60 + l] = stm_idx[(pblk + p) * 30 + l];
        } else if (e < 960) {
            int e2 = e - 480;
            int p = e2 / 30, l = e2 - p * 30;
            sidx[p * 60 + 30 + l] = nstm_idx[(pblk + p) * 30 + l];
        }
    }
    __syncthreads();

    // ---- bag gather + sum + clip, 2 halves x 4 concurrent bags ----
    const unsigned int laneoff = lane << 2;     // uint offset into a 256-uint row
#pragma unroll 1
    for (int half = 0; half < 2; ++half) {
        const int  bagbase = w * 8 + half * 4;
        const int* ids     = sidx + bagbase * 30;

        float ac[4][8];
#pragma unroll
        for (int b = 0; b < 4; ++b)
#pragma unroll
            for (int j = 0; j < 8; ++j) ac[b][j] = 0.f;

#pragma unroll 1
        for (int lc = 0; lc < 30; lc += 2) {
            // batch the 8 index reads (LDS broadcast) ahead of the loads
            int id[4][2];
#pragma unroll
            for (int b = 0; b < 4; ++b) {
                id[b][0] = ids[b * 30 + lc];
                id[b][1] = ids[b * 30 + lc + 1];
            }
            // 8 independent 16B gathers in flight
            uint4 v[4][2];
#pragma unroll
            for (int c = 0; c < 2; ++c)
#pragma unroll
                for (int b = 0; b < 4; ++b)
                    v[b][c] = *(const uint4*)(embbf + (size_t)id[b][c] * 256 + laneoff);
            // consume
#pragma unroll
            for (int c = 0; c < 2; ++c)
#pragma unroll
                for (int b = 0; b < 4; ++b) {
                    const uint4 u = v[b][c];
                    ac[b][0] += __uint_as_float(u.x << 16);
                    ac[b][1] += __uint_as_float(u.x & 0xffff0000u);
                    ac[b][2] += __uint_as_float(u.y << 16);
                    ac[b][3] += __uint_as_float(u.y & 0xffff0000u);
                    ac[b][4] += __uint_as_float(u.z << 16);
                    ac[b][5] += __uint_as_float(u.z & 0xffff0000u);
                    ac[b][6] += __uint_as_float(u.w << 16);
                    ac[b][7] += __uint_as_float(u.w & 0xffff0000u);
                }
        }
        // write out the 4 bags (clip -> bf16 pack -> swizzled LDS store)
#pragma unroll
        for (int b = 0; b < 4; ++b) {
            const int bag  = bagbase + b;
            const int p    = bag >> 1;
            const int side = bag & 1;
            uint4 pk;
            pk.x = f2bf(clip01(ac[b][0])) | (f2bf(clip01(ac[b][1])) << 16);
            pk.y = f2bf(clip01(ac[b][2])) | (f2bf(clip01(ac[b][3])) << 16);
            pk.z = f2bf(clip01(ac[b][4])) | (f2bf(clip01(ac[b][5])) << 16);
            pk.w = f2bf(clip01(ac[b][6])) | (f2bf(clip01(ac[b][7])) << 16);
            const int col  = side * 1024 + lane * 16;
            const int addr = p * 2048 + (col ^ ((p & 7) << 4));
            *(uint4*)(xb + addr) = pk;
        }
    }
    __syncthreads();

    // ---- layer1 GEMM via MFMA (M=16, N=128, K=1024) ----
    const int l15 = lane & 15, lg = lane >> 4, lq = lane & 7;
    f32x4 acc0 = {}, acc1 = {};
    const int arow = l15 * 2048;
    const bf16x8* w1v = (const bf16x8*)w1f;
#pragma unroll 4
    for (int ks = 0; ks < 32; ++ks) {
        const int acol = (ks * 64 + lg * 16) ^ (lq << 4);
        bf16x8 a0  = *(const bf16x8*)(xb + arow + acol);
        bf16x8 bf0 = w1v[((2 * w + 0) * 32 + ks) * 64 + lane];
        bf16x8 bf1 = w1v[((2 * w + 1) * 32 + ks) * 64 + lane];
        acc0 = __builtin_amdgcn_mfma_f32_16x16x32_bf16(a0, bf0, acc0, 0, 0, 0);
        acc1 = __builtin_amdgcn_mfma_f32_16x16x32_bf16(a0, bf1, acc1, 0, 0, 0);
    }
    __syncthreads();   // x tile dead; smem becomes h1/w2/h2

    // ---- epilogue: bias + clip -> h1[16][132] ----
    {
        const int o0 = (2 * w + 0) * 16 + l15;
        const int o1 = (2 * w + 1) * 16 + l15;
        const float bb0 = b1[o0], bb1 = b1[o1];
#pragma unroll
        for (int r = 0; r < 4; ++r) {
            int p0 = lg * 4 + r;                // 0..15
            h1[p0 * 132 + o0] = clip01(acc0[r] + bb0);
            h1[p0 * 132 + o1] = clip01(acc1[r] + bb1);
        }
    }
    // stage W2 (32x128): 4096 floats, 16 per thread
#pragma unroll
    for (int i = 0; i < 16; ++i) {
        int f = t + i * 256;
        int o = f >> 7, k = f & 127;
        w2[o * 132 + k] = W2[o * 128 + k];
    }
    __syncthreads();

    // ---- layer2: 16 pos x 32 out; thread -> pos t>>4, 2 outputs ----
    {
        const int p2 = t >> 4;
        const int ob = (t & 15) * 2;
        float s0 = b2[ob], s1 = b2[ob + 1];
#pragma unroll
        for (int k4 = 0; k4 < 32; ++k4) {
            float4 h4 = *(const float4*)(h1 + p2 * 132 + k4 * 4);
            float4 wa = *(const float4*)(w2 + ob * 132 + k4 * 4);
            float4 wb = *(const float4*)(w2 + (ob + 1) * 132 + k4 * 4);
            s0 += h4.x * wa.x + h4.y * wa.y + h4.z * wa.z + h4.w * wa.w;
            s1 += h4.x * wb.x + h4.y * wb.y + h4.z * wb.z + h4.w * wb.w;
        }
        h2[p2 * 33 + ob]     = clip01(s0);
        h2[p2 * 33 + ob + 1] = clip01(s1);
    }
    __syncthreads();

    // ---- layer3 + tanh ----
    if (t < MT) {
        float s = b3[0];
#pragma unroll
        for (int k = 0; k < 32; ++k) s += h2[t * 33 + k] * W3[k];
        out[pblk + t] = tanhf(s);
    }
}

// ---------------------------------------------------------------------------
extern "C" void kernel_launch(void* const* d_in, const int* in_sizes, int n_in,
                              void* d_out, int out_size, void* d_ws, size_t ws_size,
                              hipStream_t stream) {
    const int*   stm_idx  = (const int*)  d_in[0];
    const int*   nstm_idx = (const int*)  d_in[2];
    const float* emb      = (const float*)d_in[4];
    const float* W1       = (const float*)d_in[5];
    const float* b1       = (const float*)d_in[6];
    const float* W2       = (const float*)d_in[7];
    const float* b2       = (const float*)d_in[8];
    const float* W3       = (const float*)d_in[9];
    const float* b3       = (const float*)d_in[10];
    float*       out      = (float*)d_out;

    unsigned int* embbf = (unsigned int*)d_ws;                       // 41,943,040 B
    unsigned int* w1f   = (unsigned int*)((char*)d_ws + 41943040);   // 262,144 B

    cvt_emb<<<2048, 256, 0, stream>>>(emb, embbf);
    prep_w1<<<64, 256, 0, stream>>>(W1, w1f);
    nnue_fused<<<NPOS / MT, 256, 0, stream>>>(stm_idx, nstm_idx, embbf, w1f,
                                              b1, W2, b2, W3, b3, out);
}